// Round 1
// baseline (299.987 us; speedup 1.0000x reference)
//
#include <hip/hip_runtime.h>
#include <math.h>

// ContinuousPool: 10x [cur += p*(maxpool3x3_same(cur)-cur)] then avgpool2x2.
// One block per (n,c) plane (3072 blocks = 12/CU). Each thread owns an 8x8
// register tile. Horizontal 3-max halo via DPP row_shr/row_shl (16-lane DPP
// row == tx group; bound lanes get -inf == reduce_window padding). Vertical
// halo: only hmax of tile boundary rows round-trips through LDS (8 b128/step).

#define TSTEPS 10
#define PW 128
#define PH 128
#define HPITCH 132  // 32-row LDS h-halo buffer, pitch padded for bank spread

__device__ __forceinline__ float dpp_recv_left(float x) {
    // row_shr:1 -> lane i gets lane i-1 (within 16-lane DPP row); row-lane 0 -> old(-inf)
    int r = __builtin_amdgcn_update_dpp((int)0xff800000, __float_as_int(x),
                                        0x111, 0xf, 0xf, false);
    return __int_as_float(r);
}
__device__ __forceinline__ float dpp_recv_right(float x) {
    // row_shl:1 -> lane i gets lane i+1; row-lane 15 -> old(-inf)
    int r = __builtin_amdgcn_update_dpp((int)0xff800000, __float_as_int(x),
                                        0x101, 0xf, 0xf, false);
    return __int_as_float(r);
}

__device__ __forceinline__ float max3f(float a, float b, float c) {
    return fmaxf(fmaxf(a, b), c);
}

// h[c] = max(v[c-1], v[c], v[c+1]) over the thread's 8-wide row, halo via DPP.
__device__ __forceinline__ void hmax_row(const float* v, float* h) {
    float vl = dpp_recv_left(v[7]);   // left neighbor's rightmost col = my x0-1
    float vr = dpp_recv_right(v[0]);  // right neighbor's leftmost col = my x0+8
    h[0] = max3f(vl, v[0], v[1]);
#pragma unroll
    for (int c = 1; c < 7; ++c) h[c] = max3f(v[c-1], v[c], v[c+1]);
    h[7] = max3f(v[6], v[7], vr);
}

__global__ __launch_bounds__(256, 3)
void cpool_kernel(const float* __restrict__ x, const float* __restrict__ ps,
                  float* __restrict__ out) {
    __shared__ float hbuf[32 * HPITCH];  // 16.5 KB: h of each tile-band's row0/row7

    const int b  = blockIdx.x;          // plane id = n*96 + c
    const int ch = b % 96;
    const float p = ps[ch];

    const int tid = threadIdx.x;
    const int tx = tid & 15;            // == lane%16 == DPP row-lane
    const int ty = tid >> 4;
    const int x0 = tx << 3;
    const int y0 = ty << 3;

    const float* __restrict__ xp = x + (size_t)b * (PH * PW);

    float cur[8][8];
#pragma unroll
    for (int r = 0; r < 8; ++r) {
        const float4 a  = *(const float4*)(xp + (y0 + r) * PW + x0);
        const float4 bq = *(const float4*)(xp + (y0 + r) * PW + x0 + 4);
        cur[r][0] = a.x;  cur[r][1] = a.y;  cur[r][2] = a.z;  cur[r][3] = a.w;
        cur[r][4] = bq.x; cur[r][5] = bq.y; cur[r][6] = bq.z; cur[r][7] = bq.w;
    }

    const float NEG = -__builtin_huge_valf();

#pragma unroll 1
    for (int t = 0; t < TSTEPS; ++t) {
        // ---- phase 1: hmax of boundary rows -> LDS ----
        float hTop[8], hBot[8];
        hmax_row(cur[0], hTop);
        hmax_row(cur[7], hBot);

        *(float4*)&hbuf[(2*ty)   * HPITCH + x0]     = make_float4(hTop[0], hTop[1], hTop[2], hTop[3]);
        *(float4*)&hbuf[(2*ty)   * HPITCH + x0 + 4] = make_float4(hTop[4], hTop[5], hTop[6], hTop[7]);
        *(float4*)&hbuf[(2*ty+1) * HPITCH + x0]     = make_float4(hBot[0], hBot[1], hBot[2], hBot[3]);
        *(float4*)&hbuf[(2*ty+1) * HPITCH + x0 + 4] = make_float4(hBot[4], hBot[5], hBot[6], hBot[7]);

        __syncthreads();

        // ---- phase 2: read vertical h-halo (rows y0-1 and y0+8) ----
        float hm[8], hnx[8];
        if (ty > 0) {
            float4 a  = *(const float4*)&hbuf[(2*ty - 1) * HPITCH + x0];
            float4 bq = *(const float4*)&hbuf[(2*ty - 1) * HPITCH + x0 + 4];
            hm[0] = a.x;  hm[1] = a.y;  hm[2] = a.z;  hm[3] = a.w;
            hm[4] = bq.x; hm[5] = bq.y; hm[6] = bq.z; hm[7] = bq.w;
        } else {
#pragma unroll
            for (int c = 0; c < 8; ++c) hm[c] = NEG;
        }
        if (ty < 15) {
            float4 a  = *(const float4*)&hbuf[(2*ty + 2) * HPITCH + x0];
            float4 bq = *(const float4*)&hbuf[(2*ty + 2) * HPITCH + x0 + 4];
            hnx[0] = a.x;  hnx[1] = a.y;  hnx[2] = a.z;  hnx[3] = a.w;
            hnx[4] = bq.x; hnx[5] = bq.y; hnx[6] = bq.z; hnx[7] = bq.w;
        } else {
#pragma unroll
            for (int c = 0; c < 8; ++c) hnx[c] = NEG;
        }

        // ---- phase 3: rolling vmax + lerp (h window: hm, hc, hn) ----
        float hc[8];
#pragma unroll
        for (int c = 0; c < 8; ++c) hc[c] = hTop[c];

#pragma unroll
        for (int r = 0; r < 8; ++r) {
            float hn[8];
            if (r < 6) {
                hmax_row(cur[r + 1], hn);      // cur[r+1] still pre-update here
            } else if (r == 6) {
#pragma unroll
                for (int c = 0; c < 8; ++c) hn[c] = hBot[c];
            } else {
#pragma unroll
                for (int c = 0; c < 8; ++c) hn[c] = hnx[c];
            }
#pragma unroll
            for (int c = 0; c < 8; ++c) {
                float v = max3f(hm[c], hc[c], hn[c]);
                cur[r][c] = fmaf(p, v - cur[r][c], cur[r][c]);
            }
#pragma unroll
            for (int c = 0; c < 8; ++c) { hm[c] = hc[c]; hc[c] = hn[c]; }
        }

        __syncthreads();  // protect hbuf before next step's writes
    }

    // ---- epilogue: 2x2 avg pool, write 4x4 outputs per thread ----
    float* __restrict__ op = out + (size_t)b * (64 * 64);
#pragma unroll
    for (int r2 = 0; r2 < 4; ++r2) {
        float4 o;
        o.x = 0.25f * (cur[2*r2][0] + cur[2*r2][1] + cur[2*r2+1][0] + cur[2*r2+1][1]);
        o.y = 0.25f * (cur[2*r2][2] + cur[2*r2][3] + cur[2*r2+1][2] + cur[2*r2+1][3]);
        o.z = 0.25f * (cur[2*r2][4] + cur[2*r2][5] + cur[2*r2+1][4] + cur[2*r2+1][5]);
        o.w = 0.25f * (cur[2*r2][6] + cur[2*r2][7] + cur[2*r2+1][6] + cur[2*r2+1][7]);
        *(float4*)(op + (size_t)((ty * 4 + r2) * 64 + tx * 4)) = o;
    }
}

extern "C" void kernel_launch(void* const* d_in, const int* in_sizes, int n_in,
                              void* d_out, int out_size, void* d_ws, size_t ws_size,
                              hipStream_t stream) {
    const float* x  = (const float*)d_in[0];   // (32,96,128,128) fp32
    const float* ps = (const float*)d_in[1];   // (1,96,1,1) fp32
    float* out = (float*)d_out;                // (32,96,64,64) fp32
    (void)in_sizes; (void)n_in; (void)out_size; (void)d_ws; (void)ws_size;

    cpool_kernel<<<dim3(32 * 96), dim3(256), 0, stream>>>(x, ps, out);
}

// Round 2
// 292.920 us; speedup vs baseline: 1.0241x; 1.0241x over previous
//
#include <hip/hip_runtime.h>

// ContinuousPool: 10x [cur += p*(maxpool3x3_same(cur)-cur)] then avgpool2x2.
// One block (512 thr) per (n,c) plane; thread tile = 4 rows x 8 cols.
// Horizontal 3-max halo via DPP row_shr/row_shl (tx == 16-lane DPP row-lane;
// out-of-row lanes receive old = -inf == reduce_window padding).
// Vertical halo: only hmax of tile boundary rows (top/bot) goes through LDS.
// Double-buffered LDS -> ONE barrier per timestep. LDS row stride 132 floats
// (528B = 16 mod 128) so ty-consecutive rows shift start banks by 4 ->
// b128 accesses cover all 8 aligned bank-quads (floor-optimal).

#define TSTEPS 10
#define PW 128
#define HP 132
#define HROWS 31

__device__ __forceinline__ float dpp_left(float x) {
    // row_shr:1 -> lane i gets lane i-1 within its 16-lane DPP row; row-lane 0 -> old(-inf)
    int r = __builtin_amdgcn_update_dpp((int)0xff800000, __float_as_int(x),
                                        0x111, 0xf, 0xf, false);
    return __int_as_float(r);
}
__device__ __forceinline__ float dpp_right(float x) {
    // row_shl:1 -> lane i gets lane i+1; row-lane 15 -> old(-inf)
    int r = __builtin_amdgcn_update_dpp((int)0xff800000, __float_as_int(x),
                                        0x101, 0xf, 0xf, false);
    return __int_as_float(r);
}

__device__ __forceinline__ float max3f(float a, float b, float c) {
    return fmaxf(fmaxf(a, b), c);   // folds to v_max3_f32
}

// h[c] = max(v[c-1], v[c], v[c+1]) over the thread's 8-wide row, halo via DPP.
__device__ __forceinline__ void hmax_row(const float* v, float* h) {
    float vl = dpp_left(v[7]);   // left neighbor thread's rightmost col
    float vr = dpp_right(v[0]);  // right neighbor thread's leftmost col
    h[0] = max3f(vl, v[0], v[1]);
#pragma unroll
    for (int c = 1; c < 7; ++c) h[c] = max3f(v[c - 1], v[c], v[c + 1]);
    h[7] = max3f(v[6], v[7], vr);
}

__device__ __forceinline__ void ld8(const float* a, float* d) {
    float4 u = ((const float4*)a)[0], v = ((const float4*)a)[1];
    d[0] = u.x; d[1] = u.y; d[2] = u.z; d[3] = u.w;
    d[4] = v.x; d[5] = v.y; d[6] = v.z; d[7] = v.w;
}
__device__ __forceinline__ void st8(float* a, const float* d) {
    ((float4*)a)[0] = make_float4(d[0], d[1], d[2], d[3]);
    ((float4*)a)[1] = make_float4(d[4], d[5], d[6], d[7]);
}

// One timestep. topBuf[i] holds hTop of tile (i+1); botBuf[i] holds hBot of tile i.
__device__ __forceinline__ void do_step(float cur[4][8], float p, int tx, int ty,
                                        float* __restrict__ topBuf,
                                        float* __restrict__ botBuf) {
    const float NEG = -__builtin_huge_valf();
    const int x0 = tx * 8;

    float hTop[8], hBot[8];
    hmax_row(cur[0], hTop);
    hmax_row(cur[3], hBot);

    if (ty > 0)  st8(topBuf + (ty - 1) * HP + x0, hTop);
    if (ty < 31) st8(botBuf + ty * HP + x0, hBot);

    __syncthreads();

    float hm[8], hnx[8];
    if (ty > 0) {
        ld8(botBuf + (ty - 1) * HP + x0, hm);      // hBot of tile ty-1
    } else {
#pragma unroll
        for (int c = 0; c < 8; ++c) hm[c] = NEG;
    }
    if (ty < 31) {
        ld8(topBuf + ty * HP + x0, hnx);           // hTop of tile ty+1
    } else {
#pragma unroll
        for (int c = 0; c < 8; ++c) hnx[c] = NEG;
    }

    // rolling vertical 3-max + lerp; h-window rows: hm, hc, hn
    float hc[8];
#pragma unroll
    for (int c = 0; c < 8; ++c) hc[c] = hTop[c];

#pragma unroll
    for (int r = 0; r < 4; ++r) {
        float hn[8];
        if (r < 2) {
            hmax_row(cur[r + 1], hn);              // cur[r+1] still pre-update
        } else if (r == 2) {
#pragma unroll
            for (int c = 0; c < 8; ++c) hn[c] = hBot[c];
        } else {
#pragma unroll
            for (int c = 0; c < 8; ++c) hn[c] = hnx[c];
        }
#pragma unroll
        for (int c = 0; c < 8; ++c) {
            float v = max3f(hm[c], hc[c], hn[c]);
            cur[r][c] = fmaf(p, v - cur[r][c], cur[r][c]);
        }
#pragma unroll
        for (int c = 0; c < 8; ++c) { hm[c] = hc[c]; hc[c] = hn[c]; }
    }
    // no trailing barrier: next step uses the other LDS buffer; re-use of this
    // buffer happens after the NEXT step's barrier, by which time all waves'
    // reads here have completed (data consumed before that barrier).
}

__global__ __launch_bounds__(512, 4)
void cpool_kernel(const float* __restrict__ x, const float* __restrict__ ps,
                  float* __restrict__ out) {
    __shared__ float lds[2][2][HROWS * HP];   // [buf][top=0/bot=1] : 65,472 B

    const int b = blockIdx.x;                 // plane id = n*96 + c
    const float p = ps[b % 96];

    const int tx = threadIdx.x & 15;          // DPP row-lane
    const int ty = threadIdx.x >> 4;          // 0..31, 4 rows each
    const int x0 = tx * 8;
    const int y0 = ty * 4;

    const float* __restrict__ xp = x + (size_t)b * (PW * PW);

    float cur[4][8];
#pragma unroll
    for (int r = 0; r < 4; ++r) ld8(xp + (y0 + r) * PW + x0, cur[r]);

#pragma unroll 1
    for (int tt = 0; tt < TSTEPS / 2; ++tt) {
        do_step(cur, p, tx, ty, lds[0][0], lds[0][1]);
        do_step(cur, p, tx, ty, lds[1][0], lds[1][1]);
    }

    // epilogue: 2x2 avg pool -> 2 rows x 4 cols per thread
    float* __restrict__ op = out + (size_t)b * (64 * 64);
#pragma unroll
    for (int r2 = 0; r2 < 2; ++r2) {
        float4 o;
        o.x = 0.25f * (cur[2*r2][0] + cur[2*r2][1] + cur[2*r2+1][0] + cur[2*r2+1][1]);
        o.y = 0.25f * (cur[2*r2][2] + cur[2*r2][3] + cur[2*r2+1][2] + cur[2*r2+1][3]);
        o.z = 0.25f * (cur[2*r2][4] + cur[2*r2][5] + cur[2*r2+1][4] + cur[2*r2+1][5]);
        o.w = 0.25f * (cur[2*r2][6] + cur[2*r2][7] + cur[2*r2+1][6] + cur[2*r2+1][7]);
        *(float4*)(op + (size_t)((2 * ty + r2) * 64 + tx * 4)) = o;
    }
}

extern "C" void kernel_launch(void* const* d_in, const int* in_sizes, int n_in,
                              void* d_out, int out_size, void* d_ws, size_t ws_size,
                              hipStream_t stream) {
    const float* x  = (const float*)d_in[0];   // (32,96,128,128) fp32
    const float* ps = (const float*)d_in[1];   // (1,96,1,1) fp32
    float* out = (float*)d_out;                // (32,96,64,64) fp32
    (void)in_sizes; (void)n_in; (void)out_size; (void)d_ws; (void)ws_size;

    cpool_kernel<<<dim3(32 * 96), dim3(512), 0, stream>>>(x, ps, out);
}